// Round 19
// baseline (932.891 us; speedup 1.0000x reference)
//
#include <hip/hip_runtime.h>
#include <hip/hip_bf16.h>

#define NB 22
#define NFR_B 7499
#define BATCH 32
#define ROWLEN 960000
#define NFTOT (BATCH * NFR_B)
#define CPR 235                 // 32-frame chunks per batch row (234 full + ragged)
#define NCHUNK (BATCH * CPR)    // 7520

typedef float f32x16 __attribute__((ext_vector_type(16)));
typedef short short8 __attribute__((ext_vector_type(8)));

// A matrix: [rowblock rb(8)][ks(16)][lane(64)][j(8)] bf16.
// rb<4: re of bin 32rb+col ; rb>=4: im of bin 32(rb-4)+col ; k = 16ks+8h+j
__device__ __align__(16) unsigned short g_awf[65536];

__global__ void gen_a_kernel() {
    const int idx = blockIdx.x * blockDim.x + threadIdx.x;  // 0..65535
    const int j = idx & 7;
    const int lane = (idx >> 3) & 63;
    const int ks = (idx >> 9) & 15;
    const int rb = idx >> 13;
    const int bin = 32 * (rb & 3) + (lane & 31);
    const int ri = rb >> 2;
    const int k = 16 * ks + 8 * (lane >> 5) + j;
    const float PI = 3.14159265358979323846f;
    const float win = sinf(PI * (float)k / 256.0f);
    const int bk = (bin * k) & 255;
    const float ph = 6.28318530717958648f * (float)bk / 256.0f;
    const float val = win * (ri ? sinf(ph) : cosf(ph));
    __hip_bfloat16 b = __float2bfloat16(val);
    g_awf[idx] = *reinterpret_cast<unsigned short*>(&b);
}

__device__ constexpr int BND[22] = {0,4,8,12,16,20,24,28,32,40,44,48,52,56,64,72,80,88,96,104,112,128};
__device__ constexpr float Wfn(int c, int k) {
    int j = 0;
    for (int t = 1; t < 21; ++t) if (k >= BND[t]) j = t;
    const float alpha = (float)(k - BND[j]) / (float)(BND[j + 1] - BND[j]);
    float w = 0.0f;
    if (c == j)     w = 1.0f - alpha;
    if (c == j + 1) w = alpha;
    if (c == 0 || c == 21) w *= 2.0f;
    return w;
}

struct fpair { float A, B; };
__device__ __forceinline__ fpair bh32(float v) {
    const unsigned u = __float_as_uint(v);
    const auto p = __builtin_amdgcn_permlane32_swap(u, u, false, false);
    fpair r; r.A = __uint_as_float(p[0]); r.B = __uint_as_float(p[1]); return r;
}
__device__ __forceinline__ unsigned pk(float hi, float lo) {
    return __builtin_amdgcn_perm(__float_as_uint(hi), __float_as_uint(lo), 0x07060302u);
}
__device__ __forceinline__ short8 mk_bfrag(float4 lo, float4 hi) {
    int4 u;
    u.x = (int)pk(lo.y, lo.x);
    u.y = (int)pk(lo.w, lo.z);
    u.z = (int)pk(hi.y, hi.x);
    u.w = (int)pk(hi.w, hi.z);
    return *reinterpret_cast<short8*>(&u);
}

template<int P>
__device__ __forceinline__ void foldP(const f32x16& accr, const f32x16& acci,
                                      float hf, float* partial) {
    #pragma unroll
    for (int r = 0; r < 16; ++r) {
        const float pw = accr[r] * accr[r] + acci[r] * acci[r];
        const int bin0 = 32 * P + (r & 3) + 8 * (r >> 2);
        #pragma unroll
        for (int c = 0; c < NB; ++c) {
            const float w0 = Wfn(c, bin0);
            const float w1 = Wfn(c, bin0 + 4);
            if (w0 != 0.0f || w1 != 0.0f)
                partial[c] = fmaf(fmaf(hf, w1 - w0, w0), pw, partial[c]);
        }
    }
}

__global__ __launch_bounds__(256, 3)
void feat_mfma3(const float* __restrict__ x, float* __restrict__ out) {
    const int lane = threadIdx.x & 63;
    const int wid  = threadIdx.x >> 6;      // wave owns rowblocks {wid, wid+4}
    const int col  = lane & 31;
    const int h    = lane >> 5;
    const float hf = (float)h;

    __shared__ float xs[33 * 128];          // rows of 512B = 32 x 16B slots, slot-XOR swizzle
    __shared__ float comb[4 * 32 * 23];     // padded x23 (coprime 32)

    const unsigned short* aR = g_awf + ((size_t)wid       * 16) * 64 * 8;
    const unsigned short* aI = g_awf + ((size_t)(wid + 4) * 16) * 64 * 8;

    for (int ch = blockIdx.x; ch < NCHUNK; ch += gridDim.x) {
        const int row = ch / CPR;
        const int loc = ch - row * CPR;
        const int t   = loc * 32;
        const float* xrow = x + (size_t)row * ROWLEN;

        // stage 33 x 128 floats, coalesced, slot-XOR swizzled; clamp = row tail window
        for (int i = threadIdx.x; i < 33 * 32; i += 256) {
            const int jj = i >> 5;
            const int of = i & 31;
            int src = (t + jj) * 128;
            if (src > ROWLEN - 128) src = ROWLEN - 128;
            const float4 v = *(const float4*)(xrow + src + of * 4);
            const int dst = jj * 512 + ((of ^ (jj & 31)) << 4);
            *(float4*)((char*)xs + dst) = v;
        }
        __syncthreads();   // (1) staging complete

        // 32 MFMAs: A streamed from L2, x from LDS
        f32x16 accr = {}; f32x16 acci = {};
        #pragma unroll
        for (int ks = 0; ks < 16; ++ks) {
            const short8 ar = *(const short8*)(aR + ((size_t)ks * 64 + lane) * 8);
            const short8 ai = *(const short8*)(aI + ((size_t)ks * 64 + lane) * 8);
            const int kb = 16 * ks + 8 * h;
            const int jj = col + (kb >> 7);
            const int sl = (kb & 127) >> 2;            // 16B slot within row
            const int sw = jj & 31;
            const int a1 = jj * 512 + (((sl + 0) ^ sw) << 4);
            const int a2 = jj * 512 + (((sl + 1) ^ sw) << 4);
            const float4 lo = *(const float4*)((const char*)xs + a1);
            const float4 hi = *(const float4*)((const char*)xs + a2);
            const short8 bf = mk_bfrag(lo, hi);
            accr = __builtin_amdgcn_mfma_f32_32x32x16_bf16(ar, bf, accr, 0, 0, 0);
            acci = __builtin_amdgcn_mfma_f32_32x32x16_bf16(ai, bf, acci, 0, 0, 0);
        }

        // fold pw into band partials (compile-time weights)
        float partial[NB];
        #pragma unroll
        for (int c = 0; c < NB; ++c) partial[c] = 0.0f;
        switch (wid) {
            case 0: foldP<0>(accr, acci, hf, partial); break;
            case 1: foldP<1>(accr, acci, hf, partial); break;
            case 2: foldP<2>(accr, acci, hf, partial); break;
            default: foldP<3>(accr, acci, hf, partial); break;
        }
        #pragma unroll
        for (int c = 0; c < NB; ++c) {
            const fpair q = bh32(partial[c]);
            partial[c] = q.A + q.B;
        }
        if (lane < 32) {
            #pragma unroll
            for (int c = 0; c < NB; ++c)
                comb[(wid * 32 + col) * 23 + c] = partial[c];
        }
        __syncthreads();   // (2) comb ready; also seals xs reads before next staging

        // epilogue: sum 4 rowblock-partials, log, Chebyshev DCT (verified R17/R18)
        const int fr = t + col;
        if (fr < NFR_B) {
            float lg[NB];
            #pragma unroll
            for (int c = 0; c < NB; ++c) {
                const float b = comb[(0 * 32 + col) * 23 + c]
                              + comb[(1 * 32 + col) * 23 + c]
                              + comb[(2 * 32 + col) * 23 + c]
                              + comb[(3 * 32 + col) * 23 + c];
                lg[c] = __log2f(b);
            }
            const float PI = 3.14159265358979323846f;
            const float SC = 0.30102999566398120f * 0.30151134457776363f;
            float* o = out + ((size_t)row * NFR_B + fr) * NB;
            #pragma unroll
            for (int ol = 0; ol < 11; ++ol) {
                const int oc = h * 11 + ol;
                const float th = PI * (float)oc / 22.0f;
                const float cth2 = 2.0f * cosf(th);
                float fm = cosf(0.5f * th);
                float fc = fm;
                float a = fc * lg[0];
                #pragma unroll
                for (int c = 1; c < NB; ++c) {
                    const float fn = fmaf(cth2, fc, -fm);
                    fm = fc; fc = fn;
                    a = fmaf(fc, lg[c], a);
                }
                o[oc] = a * ((oc == 0) ? SC * 0.70710678118654752f : SC);
            }
        }
    }
}

extern "C" void kernel_launch(void* const* d_in, const int* in_sizes, int n_in,
                              void* d_out, int out_size, void* d_ws, size_t ws_size,
                              hipStream_t stream) {
    const float* x = (const float*)d_in[0];
    float* out = (float*)d_out;
    gen_a_kernel<<<256, 256, 0, stream>>>();
    feat_mfma3<<<768, 256, 0, stream>>>(x, out);
}

// Round 20
// 84.698 us; speedup vs baseline: 11.0144x; 11.0144x over previous
//
#include <hip/hip_runtime.h>

#define NB 22
#define NFR_B 7499
#define BATCH 32
#define ROWLEN 960000
#define NFTOT (BATCH * NFR_B)

typedef float f2 __attribute__((ext_vector_type(2)));

__constant__ int c_bands[NB] = {0,4,8,12,16,20,24,28,32,40,44,48,52,56,64,72,80,88,96,104,112,128};

// ---- cross-lane primitives ----
#define XDPP(x, CTRL) __int_as_float(__builtin_amdgcn_update_dpp(0, __float_as_int(x), CTRL, 0xF, 0xF, true))
#define XSWZ(x, PATT) __int_as_float(__builtin_amdgcn_ds_swizzle(__float_as_int(x), PATT))
#define E0S(x) XDPP(x, 0xB1)      // xor 1  (quad_perm)
#define E1S(x) XDPP(x, 0x4E)      // xor 2  (quad_perm)
#define E2S(x) XSWZ(x, 0x101F)    // xor 4  (swizzle BitMode)
#define E3S(x) XDPP(x, 0x128)     // xor 8  (row_ror:8)
#define BC32(x, B) XSWZ(x, ((B) << 5))   // broadcast lane B within 32-lane halves (B literal!)

__device__ __forceinline__ float bperm(int addr4, float v) {
    return __int_as_float(__builtin_amdgcn_ds_bpermute(addr4, __float_as_int(v)));
}
// permlane self-swap via builtin: A = lo-group broadcast, B = hi-group broadcast (VALU pipe)
struct fpair { float A, B; };
__device__ __forceinline__ fpair bh16(float v) {
    const unsigned u = __float_as_uint(v);
    const auto p = __builtin_amdgcn_permlane16_swap(u, u, false, false);
    fpair r; r.A = __uint_as_float(p[0]); r.B = __uint_as_float(p[1]); return r;
}
__device__ __forceinline__ fpair bh32(float v) {
    const unsigned u = __float_as_uint(v);
    const auto p = __builtin_amdgcn_permlane32_swap(u, u, false, false);
    fpair r; r.A = __uint_as_float(p[0]); r.B = __uint_as_float(p[1]); return r;
}
__device__ __forceinline__ f2 mk2(float v) { f2 r; r.x = v; r.y = v; return r; }
__device__ __forceinline__ f2 ex0v(f2 v) { f2 r; r.x = E0S(v.x); r.y = E0S(v.y); return r; }
__device__ __forceinline__ f2 ex1v(f2 v) { f2 r; r.x = E1S(v.x); r.y = E1S(v.y); return r; }
__device__ __forceinline__ f2 ex2v(f2 v) { f2 r; r.x = E2S(v.x); r.y = E2S(v.y); return r; }
__device__ __forceinline__ f2 ex3v(f2 v) { f2 r; r.x = E3S(v.x); r.y = E3S(v.y); return r; }
__device__ __forceinline__ f2 bpermv(int addr4, f2 v) {
    f2 r; r.x = bperm(addr4, v.x); r.y = bperm(addr4, v.y); return r;
}

// packed select-free stage: res = W1*x + W2*e
#define PSTAGE(S, EXF)                                                    \
  { const f2 exr_a = EXF(ar2), exi_a = EXF(ai2);                          \
    const f2 exr_b = EXF(br2), exi_b = EXF(bi2);                          \
    const f2 w1r = mk2(W1r[S]), w1i = mk2(W1i[S]);                        \
    const f2 w2r = mk2(W2r[S]), w2i = mk2(W2i[S]);                        \
    const f2 nar = w1r*ar2 - w1i*ai2 + w2r*exr_a - w2i*exi_a;             \
    const f2 nai = w1r*ai2 + w1i*ar2 + w2r*exi_a + w2i*exr_a;             \
    const f2 nbr = w1r*br2 - w1i*bi2 + w2r*exr_b - w2i*exi_b;             \
    const f2 nbi = w1r*bi2 + w1i*br2 + w2r*exi_b + w2i*exr_b;             \
    ar2 = nar; ai2 = nai; br2 = nbr; bi2 = nbi; }

// broadcast-halves stage (permlane): res = A + Ws*B
#define BHSTAGE(BH, WSR, WSI)                                             \
  { const fpair arx = BH(ar2.x), ary = BH(ar2.y);                         \
    const fpair aix = BH(ai2.x), aiy = BH(ai2.y);                         \
    const fpair brx = BH(br2.x), bry = BH(br2.y);                         \
    const fpair bix = BH(bi2.x), biy = BH(bi2.y);                         \
    const f2 Aar = { arx.A, ary.A }, Bar = { arx.B, ary.B };              \
    const f2 Aai = { aix.A, aiy.A }, Bai = { aix.B, aiy.B };              \
    const f2 Abr = { brx.A, bry.A }, Bbr = { brx.B, bry.B };              \
    const f2 Abi = { bix.A, biy.A }, Bbi = { bix.B, biy.B };              \
    const f2 wr = mk2(WSR), wi = mk2(WSI);                                \
    ar2 = Aar + wr*Bar - wi*Bai;                                          \
    ai2 = Aai + wr*Bai + wi*Bar;                                          \
    br2 = Abr + wr*Bbr - wi*Bbi;                                          \
    bi2 = Abi + wr*Bbi + wi*Bbr; }

// DCT symmetric pair with LITERAL band index B: acc += coef[B]*(z[B] + sOc*z[21-B])
#define DCTPAIR(B, ACC)                                                   \
  { const float zlo = BC32(Z, B);                                         \
    const float zhi = BC32(Z, 21 - (B));                                  \
    ACC = fmaf(coef[B], fmaf(sOc, zhi, zlo), ACC); }

__global__ __launch_bounds__(256, 4)
void feat_kernel(const float* __restrict__ x, float* __restrict__ out) {
    const int lane = threadIdx.x & 63;
    const int wid  = threadIdx.x >> 6;
    const int gwave  = blockIdx.x * (blockDim.x >> 6) + wid;
    const int nwaves = gridDim.x * (blockDim.x >> 6);

    const float PI = 3.14159265358979323846f;

    // 7-bit bit-reversal of lane (bit6 = 0 -> r even)
    const int r = (int)(__brev((unsigned)lane) >> 25);

    float winv[4];
    #pragma unroll
    for (int j = 0; j < 4; ++j) winv[j] = sinf(PI * (float)(2 * r + j) / 256.0f);

    // select-free butterfly constants for DPP stages 1..3
    float W1r[4], W1i[4], W2r[4], W2i[4];
    #pragma unroll
    for (int s = 1; s < 4; ++s) {
        const int m = 1 << s;
        const float ang = -PI * (float)(lane & (m - 1)) / (float)m;
        const float wr = cosf(ang), wi = sinf(ang);
        const bool up = ((lane >> s) & 1) != 0;
        W1r[s] = up ? -wr : 1.0f;
        W1i[s] = up ? -wi : 0.0f;
        W2r[s] = up ? 1.0f : wr;
        W2i[s] = up ? 0.0f : wi;
    }
    const float sgn0 = (lane & 1) ? -1.0f : 1.0f;     // stage 0 (w = 1)
    // broadcast-halves signed twiddles for stages 4 (span16) and 5 (span32)
    const float sg4 = ((lane >> 4) & 1) ? -1.0f : 1.0f;
    const float ang4 = -PI * (float)(lane & 15) / 16.0f;
    const float ws4r = sg4 * cosf(ang4), ws4i = sg4 * sinf(ang4);
    const float sg5 = ((lane >> 5) & 1) ? -1.0f : 1.0f;
    const float ang5 = -PI * (float)(lane & 31) / 32.0f;
    const float ws5r = sg5 * cosf(ang5), ws5i = sg5 * sinf(ang5);

    const float w6r = cosf(-PI * (float)lane / 64.0f);
    const float w6i = sinf(-PI * (float)lane / 64.0f);
    const float c1 = cosf(PI * (float)lane / 128.0f);
    const float s1 = sinf(PI * (float)lane / 128.0f);

    // ---- band segmentation constants ----
    int seg1 = 0;
    for (int j = 1; j < 14; ++j) if (lane >= c_bands[j]) seg1 = j;
    const int wd1 = c_bands[seg1 + 1] - c_bands[seg1];
    const float a1 = (float)(lane - c_bands[seg1]) / (float)wd1;
    const float m8 = (wd1 == 8) ? 1.0f : 0.0f;
    const int bin2 = lane + 64;
    int seg2 = 14;
    for (int j = 15; j < 21; ++j) if (bin2 >= c_bands[j]) seg2 = j;
    const int wd2 = c_bands[seg2 + 1] - c_bands[seg2];
    const float a2 = (float)(bin2 - c_bands[seg2]) / (float)wd2;
    const float m16 = (seg2 == 20) ? 1.0f : 0.0f;

    // gather byte-indices (hoisted once)
    const int c = lane;
    int idxA = 0; bool selA1 = true;
    if (c >= 1 && c <= 21) {
        if (c - 1 <= 13) { idxA = c_bands[c - 1]; selA1 = true; }
        else             { idxA = c_bands[c - 1] - 64; selA1 = false; }
    }
    int idxD = 0; bool selD1 = true;
    if (c <= 20) {
        if (c <= 13) { idxD = c_bands[c]; selD1 = true; }
        else         { idxD = c_bands[c] - 64; selD1 = false; }
    }
    const int bpA = idxA << 2;
    const int bpD = idxD << 2;
    const int bpHerm = (((64 - lane) & 63) << 2);

    // DCT: symmetric-pair form. coef[21-b] = (-1)^oc * coef[b]
    const int oc = lane & 31;
    float coef[11];
    {
        const float norm = 0.30102999566398120f * sqrtf(2.0f / (float)NB) *
                           ((oc == 0) ? 0.70710678118654752f : 1.0f);
        #pragma unroll
        for (int b = 0; b < 11; ++b)
            coef[b] = norm * cosf(PI / (float)NB * ((float)b + 0.5f) * (float)oc);
    }
    const float sOc = (oc & 1) ? -1.0f : 1.0f;
    // pw scaled x4 (dropped 0.5 in E/O): only row oc=0 has nonzero coef sum
    const float accInit = (oc == 0) ? (-2.0f * 0.30102999566398120f * sqrtf(22.0f)) : 0.0f;

    // even-sized contiguous frame chunk per wave
    const int chunk = (((NFTOT + nwaves - 1) / nwaves) + 1) & ~1;
    int f0 = gwave * chunk;
    if (f0 >= NFTOT) return;
    int f1 = f0 + chunk; if (f1 > NFTOT) f1 = NFTOT;
    const int f0u = __builtin_amdgcn_readfirstlane(f0);
    const int f1u = __builtin_amdgcn_readfirstlane(f1);

    int bb = f0u / NFR_B;
    int t0 = f0u - bb * NFR_B;
    const float* p0 = x + (size_t)bb * ROWLEN + (size_t)t0 * 128;
    int t1 = t0 + 1;
    const float* p1 = p0 + 128;
    if (t1 == NFR_B) { t1 = 0; p1 += 128; }

    float* ob = out + (size_t)f0u * NB + ((lane < 32) ? oc : (NB + oc));

    float4 v0 = *(const float4*)(p0 + 2 * r);
    float4 v1 = *(const float4*)(p1 + 2 * r);

    for (int f = f0u; f < f1u; f += 2) {
        // next-pair pointers + prefetch
        int nt0 = t1 + 1; const float* np0 = p1 + 128;
        if (nt0 == NFR_B) { nt0 = 0; np0 += 128; }
        int nt1 = nt0 + 1; const float* np1 = np0 + 128;
        if (nt1 == NFR_B) { nt1 = 0; np1 += 128; }
        float4 nv0 = v0, nv1 = v1;
        if (f + 2 < f1u) {
            nv0 = *(const float4*)(np0 + 2 * r);
            nv1 = *(const float4*)(np1 + 2 * r);
        }

        // window + pack (frame0 in .x, frame1 in .y)
        f2 ar2 = { v0.x * winv[0], v1.x * winv[0] };
        f2 ai2 = { v0.y * winv[1], v1.y * winv[1] };
        f2 br2 = { v0.z * winv[2], v1.z * winv[2] };
        f2 bi2 = { v0.w * winv[3], v1.w * winv[3] };

        // stage 0: w = 1 -> res = sgn*x + e
        {
            const f2 e_ar = ex0v(ar2), e_ai = ex0v(ai2);
            const f2 e_br = ex0v(br2), e_bi = ex0v(bi2);
            const f2 s2 = mk2(sgn0);
            ar2 = s2 * ar2 + e_ar;  ai2 = s2 * ai2 + e_ai;
            br2 = s2 * br2 + e_br;  bi2 = s2 * bi2 + e_bi;
        }
        PSTAGE(1, ex1v)
        PSTAGE(2, ex2v)
        PSTAGE(3, ex3v)
        BHSTAGE(bh16, ws4r, ws4i)   // span 16 via v_permlane16_swap (VALU)
        BHSTAGE(bh32, ws5r, ws5i)   // span 32 via v_permlane32_swap (VALU)

        // span-64 stage (lane-local)
        {
            const f2 tr2 = mk2(w6r) * br2 - mk2(w6i) * bi2;
            const f2 ti2 = mk2(w6r) * bi2 + mk2(w6i) * br2;
            const f2 nar = ar2 + tr2, nai = ai2 + ti2;
            br2 = ar2 - tr2; bi2 = ai2 - ti2;
            ar2 = nar; ai2 = nai;
        }

        // Hermitian unpack (0.5 factors dropped -> pw scaled x4)
        const f2 par2 = bpermv(bpHerm, ar2), pai2 = bpermv(bpHerm, ai2);
        const f2 pbr2 = bpermv(bpHerm, br2), pbi2 = bpermv(bpHerm, bi2);
        const f2 P1r = (lane == 0) ? par2 : pbr2, P1i = (lane == 0) ? pai2 : pbi2;
        const f2 P2r = (lane == 0) ? pbr2 : par2, P2i = (lane == 0) ? pbi2 : pai2;

        f2 Er = ar2 + P1r, Ei = ai2 - P1i;
        f2 Or_ = ar2 - P1r, Oi = ai2 + P1i;
        const f2 X1r = Er + mk2(c1) * Oi - mk2(s1) * Or_;
        const f2 X1i = Ei - mk2(c1) * Or_ - mk2(s1) * Oi;
        const f2 pw1 = X1r * X1r + X1i * X1i;

        Er = br2 + P2r; Ei = bi2 - P2i;
        Or_ = br2 - P2r; Oi = bi2 + P2i;
        const f2 X2r = Er - mk2(s1) * Oi - mk2(c1) * Or_;
        const f2 X2i = Ei + mk2(s1) * Or_ - mk2(c1) * Oi;
        const f2 pw2 = X2r * X2r + X2i * X2i;

        // segmented band reduction
        f2 S1 = pw1, T1 = mk2(a1) * pw1;
        S1 = S1 + ex0v(S1); T1 = T1 + ex0v(T1);
        S1 = S1 + ex1v(S1); T1 = T1 + ex1v(T1);
        S1 = mk2(m8) * ex2v(S1) + S1; T1 = mk2(m8) * ex2v(T1) + T1;
        const f2 D1 = S1 - T1;
        f2 S2 = pw2, T2 = mk2(a2) * pw2;
        S2 = S2 + ex0v(S2); T2 = T2 + ex0v(T2);
        S2 = S2 + ex1v(S2); T2 = T2 + ex1v(T2);
        S2 = S2 + ex2v(S2); T2 = T2 + ex2v(T2);
        S2 = mk2(m16) * ex3v(S2) + S2; T2 = mk2(m16) * ex3v(T2) + T2;
        const f2 D2 = S2 - T2;

        // per-band assembly: band c = A(seg c-1) + D(seg c); edges x2
        const f2 gA1 = bpermv(bpA, T1), gA2 = bpermv(bpA, T2);
        const f2 gD1 = bpermv(bpD, D1), gD2 = bpermv(bpD, D2);
        const f2 A_prev = selA1 ? gA1 : gA2;
        const f2 D_cur  = selD1 ? gD1 : gD2;
        f2 band = A_prev + D_cur;
        if (c == 0)  band = D_cur + D_cur;
        if (c == 21) band = A_prev + A_prev;

        f2 l2;
        l2.x = __log2f(band.x);
        l2.y = __log2f(band.y);

        // lanes 0..31 serve frame0's bands, 32..63 frame1's (permlane lo-broadcast)
        const fpair zsw = bh32(l2.y);
        const float Z = (lane < 32) ? l2.x : zsw.A;

        // symmetric-pair DCT (literal indices, two accumulator chains)
        float acc0 = accInit, acc1 = 0.0f;
        DCTPAIR(0, acc0)  DCTPAIR(1, acc1)
        DCTPAIR(2, acc0)  DCTPAIR(3, acc1)
        DCTPAIR(4, acc0)  DCTPAIR(5, acc1)
        DCTPAIR(6, acc0)  DCTPAIR(7, acc1)
        DCTPAIR(8, acc0)  DCTPAIR(9, acc1)
        DCTPAIR(10, acc0)
        if (oc < NB) *ob = acc0 + acc1;

        // advance
        v0 = nv0; v1 = nv1;
        t0 = nt0; t1 = nt1; p0 = np0; p1 = np1;
        ob += 2 * NB;
    }
}

extern "C" void kernel_launch(void* const* d_in, const int* in_sizes, int n_in,
                              void* d_out, int out_size, void* d_ws, size_t ws_size,
                              hipStream_t stream) {
    const float* x = (const float*)d_in[0];
    float* out = (float*)d_out;
    feat_kernel<<<1792, 256, 0, stream>>>(x, out);
}